// Round 10
// baseline (115.944 us; speedup 1.0000x reference)
//
#include <hip/hip_runtime.h>
#include <hip/hip_bf16.h>
#include <stdint.h>

// Chamfer loss: dist = ||x||^2 + ||y||^2 - 2 x.y via pure bf16 MFMA, K=128.
// R9 (resubmit; prior round's bench timed out before running): occupancy fix.
// 128x128 tiles, 256 threads / 4 waves (2x2), 66 KB LDS -> 2 blocks/CU: a
// co-resident block's MFMA covers this block's staging DMA + epilogue (the
// m97 implicit-overlap mechanism we never had at 1 block/CU). Whole K=128 of
// A and B staged up front (proven gload_lds geometry + XOR swizzle), ONE
// pre-MFMA sync, 64 MFMAs/wave with no in-loop barriers, LDS-combined
// epilogue (R1's proven 2x2-wave version) -> 256 atomics/block. X pre-scaled
// by -2 (exact); acc init = x2[i]+y2[j] so the accumulator IS the distance.
// R8 lesson: never commit per-wave atomics without LDS pre-combine
// (memory-side atomic line-bouncing: +46 MB HBM).

typedef __bf16  bf16x8 __attribute__((ext_vector_type(8)));
typedef float   f32x4  __attribute__((ext_vector_type(4)));

#define NPTS 8192
#define DIM  128
#define KC   128   // bf16 K (pure hi)

__device__ __forceinline__ void gload_lds16(const void* gsrc, void* ldst) {
  __builtin_amdgcn_global_load_lds(
      (const __attribute__((address_space(1))) uint32_t*)(uintptr_t)gsrc,
      (__attribute__((address_space(3))) uint32_t*)(uintptr_t)ldst,
      16, 0, 0);
}

// ---------------------------------------------------------------- prep ----
// One float4 per thread (32 threads/row). Row norms (fp32 of ORIGINAL data),
// bf16 cast of (-2x) for X / (y) for Y, min arrays -> +inf.
__global__ __launch_bounds__(256) void prep_kernel(
    const float* __restrict__ x, const float* __restrict__ y,
    unsigned short* __restrict__ Xc, unsigned short* __restrict__ Yc,
    float* __restrict__ x2, float* __restrict__ y2,
    unsigned int* __restrict__ minx, unsigned int* __restrict__ miny)
{
  const int gt  = blockIdx.x * 256 + threadIdx.x;   // 0 .. 524287
  const int row = gt >> 5;                          // 0 .. 16383
  const int seg = gt & 31;                          // float4 slot in row
  const bool isx = row < NPTS;
  const float* src        = isx ? (x  + (size_t)row * DIM) : (y  + (size_t)(row - NPTS) * DIM);
  unsigned short* dst     = isx ? (Xc + (size_t)row * KC)  : (Yc + (size_t)(row - NPTS) * KC);

  f32x4 v = *reinterpret_cast<const f32x4*>(src + seg * 4);
  float sq = v[0]*v[0] + v[1]*v[1] + v[2]*v[2] + v[3]*v[3];
  #pragma unroll
  for (int m = 1; m <= 16; m <<= 1) sq += __shfl_xor(sq, m);   // 32-lane segmented reduce
  if (seg == 0) { if (isx) x2[row] = sq; else y2[row - NPTS] = sq; }

  const float scale = isx ? -2.0f : 1.0f;           // fold the -2 into X (exact)
  unsigned short hb[4];
  #pragma unroll
  for (int i = 0; i < 4; ++i) {
    __hip_bfloat16 h = __float2bfloat16(scale * v[i]);
    hb[i] = __builtin_bit_cast(unsigned short, h);
  }
  *reinterpret_cast<ushort4*>(dst + seg * 4) = make_ushort4(hb[0], hb[1], hb[2], hb[3]);

  if (gt < NPTS)          minx[gt]        = 0x7F800000u;   // +inf
  else if (gt < 2 * NPTS) miny[gt - NPTS] = 0x7F800000u;
}

// ---------------------------------------------------------------- gemm ----
// 128x128 tile, 256 threads / 4 waves (2x2); per wave 64x64 via acc[4][4]
// of mfma_f32_16x16x32_bf16. K=128 fully staged (2 chunks of 64), one sync.
__global__ __launch_bounds__(256, 2) void chamfer_gemm(
    const unsigned short* __restrict__ Xc, const unsigned short* __restrict__ Yc,
    const float* __restrict__ x2, const float* __restrict__ y2,
    unsigned int* __restrict__ minx, unsigned int* __restrict__ miny)
{
  __shared__ alignas(16) unsigned short As[2][128 * 64];   // 16 KB each
  __shared__ alignas(16) unsigned short Bs[2][128 * 64];
  __shared__ float colminLDS[2][128];                      // dedicated scratch
  __shared__ float rowminLDS[2][128];

  const int tid  = threadIdx.x;
  const int lane = tid & 63;
  const int w    = tid >> 6;        // 0..3
  const int wr   = w >> 1;          // 0..1  (rows: wr*64)
  const int wc   = w & 1;           // 0..1  (cols: wc*64)

  // XCD map: xcd = b&7 -> bi in [xcd*8, xcd*8+8); 64x64 tile grid.
  const int b     = blockIdx.x;
  const int xcd   = b & 7;
  const int local = b >> 3;                // 0..511
  const int bi    = xcd * 8 + (local >> 6);
  const int bj    = local & 63;

  // staging geometry (proven; row stride 128 B unchanged): LDS byte =
  // row*128 + slot*16 (linear in tid), slot = tid&7, row = l*32 + (tid>>3);
  // source pre-swizzled: kgroup = slot ^ (row&7).
  const int r32  = tid >> 3;               // 0..31
  const int kgrp = (tid & 7) ^ (r32 & 7);
  const unsigned short* Abase = Xc + (size_t)(bi * 128 + r32) * KC + kgrp * 8;
  const unsigned short* Bbase = Yc + (size_t)(bj * 128 + r32) * KC + kgrp * 8;
  const int wofs = w * 1024;               // wave-uniform LDS base offset

  // ---- stage ENTIRE K=128 of A and B (16 loads/thread) ----
  #pragma unroll
  for (int kt = 0; kt < 2; ++kt) {
    #pragma unroll
    for (int l = 0; l < 4; ++l) {          // 32 rows per round
      gload_lds16(Abase + kt * 64 + (size_t)l * 32 * KC, (char*)&As[kt][0] + l * 4096 + wofs);
      gload_lds16(Bbase + kt * 64 + (size_t)l * 32 * KC, (char*)&Bs[kt][0] + l * 4096 + wofs);
    }
  }

  // ---- acc init = x2[row] + y2[col] (overlaps the staging DMA) ----
  f32x4 acc[4][4];
  {
    f32x4 xv[4]; float yv[4];
    #pragma unroll
    for (int mi = 0; mi < 4; ++mi)
      xv[mi] = *reinterpret_cast<const f32x4*>(x2 + bi * 128 + wr * 64 + mi * 16 + ((lane >> 4) << 2));
    #pragma unroll
    for (int ni = 0; ni < 4; ++ni)
      yv[ni] = y2[bj * 128 + wc * 64 + ni * 16 + (lane & 15)];
    #pragma unroll
    for (int mi = 0; mi < 4; ++mi)
      #pragma unroll
      for (int ni = 0; ni < 4; ++ni)
        #pragma unroll
        for (int r = 0; r < 4; ++r)
          acc[mi][ni][r] = xv[mi][r] + yv[ni];
  }

  __syncthreads();   // the ONLY pre-MFMA sync: A,B resident (vmcnt drained)

  // ---- 64 MFMAs/wave, no barriers, nothing in between ----
  #pragma unroll
  for (int kt = 0; kt < 2; ++kt) {
    const char* Ab = (const char*)&As[kt][0];
    const char* Bb = (const char*)&Bs[kt][0];

    bf16x8 bfr[4][2];
    #pragma unroll
    for (int ni = 0; ni < 4; ++ni) {
      const int col = wc * 64 + ni * 16 + (lane & 15);
      const int swz = (col & 7) << 4;
      #pragma unroll
      for (int ks = 0; ks < 2; ++ks) {
        const int ofs = (ks * 64 + ((lane >> 4) << 4)) ^ swz;
        bfr[ni][ks] = *reinterpret_cast<const bf16x8*>(Bb + col * 128 + ofs);
      }
    }
    #pragma unroll
    for (int mi = 0; mi < 4; ++mi) {
      const int rowl = wr * 64 + mi * 16 + (lane & 15);
      const int swz  = (rowl & 7) << 4;
      const bf16x8 a0 = *reinterpret_cast<const bf16x8*>(Ab + rowl * 128 + ((  0 + ((lane >> 4) << 4)) ^ swz));
      const bf16x8 a1 = *reinterpret_cast<const bf16x8*>(Ab + rowl * 128 + (( 64 + ((lane >> 4) << 4)) ^ swz));
      #pragma unroll
      for (int ni = 0; ni < 4; ++ni) {
        acc[mi][ni] = __builtin_amdgcn_mfma_f32_16x16x32_bf16(a0, bfr[ni][0], acc[mi][ni], 0, 0, 0);
        acc[mi][ni] = __builtin_amdgcn_mfma_f32_16x16x32_bf16(a1, bfr[ni][1], acc[mi][ni], 0, 0, 0);
      }
    }
  }

  // ---- epilogue (R1-proven 2x2-wave version): pure min reductions ----
  // column mins over this wave's 64 rows (per ni, then fold over lane>>4)
  float cm[4];
  #pragma unroll
  for (int ni = 0; ni < 4; ++ni) {
    float m = 3.0e38f;
    #pragma unroll
    for (int mi = 0; mi < 4; ++mi)
      #pragma unroll
      for (int r = 0; r < 4; ++r)
        m = fminf(m, acc[mi][ni][r]);
    cm[ni] = m;
  }
  {
    const bool hb0 = (lane & 16) != 0;
    float s0 = hb0 ? cm[0] : cm[2];
    float s1 = hb0 ? cm[1] : cm[3];
    float r0 = __shfl_xor(s0, 16);
    float r1 = __shfl_xor(s1, 16);
    float t0 = fminf(hb0 ? cm[2] : cm[0], r0);
    float t1 = fminf(hb0 ? cm[3] : cm[1], r1);
    const bool hb1 = (lane & 32) != 0;
    float s  = hb1 ? t0 : t1;
    float rr = __shfl_xor(s, 32);
    float cfin = fminf(hb1 ? t1 : t0, rr);
    const int ni = (hb0 ? 2 : 0) + (hb1 ? 1 : 0);    // bitrev2(lane>>4)
    colminLDS[wr][wc * 64 + ni * 16 + (lane & 15)] = cfin;
  }

  // row mins: reduce over ni in regs, then log-fold over the 16-lane group
  float rm[16];
  #pragma unroll
  for (int mi = 0; mi < 4; ++mi)
    #pragma unroll
    for (int r = 0; r < 4; ++r)
      rm[mi * 4 + r] = fminf(fminf(acc[mi][0][r], acc[mi][1][r]),
                             fminf(acc[mi][2][r], acc[mi][3][r]));
  #pragma unroll
  for (int b2 = 0; b2 < 4; ++b2) {
    const int  half = 8 >> b2;
    const bool up   = (lane >> b2) & 1;
    #pragma unroll
    for (int i = 0; i < half; ++i) {
      float snd = up ? rm[i] : rm[i + half];
      float rcv = __shfl_xor(snd, 1 << b2);
      rm[i] = fminf(up ? rm[i + half] : rm[i], rcv);
    }
  }
  {
    const int v = ((lane & 1) << 3) | ((lane & 2) << 1) | ((lane & 4) >> 1) | ((lane & 8) >> 3);
    const int row_local = wr * 64 + (v >> 2) * 16 + ((lane >> 4) << 2) + (v & 3);
    rowminLDS[wc][row_local] = rm[0];
  }
  __syncthreads();

  // combine the 2 waves per axis, clamp at 0, one atomic per row/col
  if (tid < 128) {
    float c = fminf(colminLDS[0][tid], colminLDS[1][tid]);
    atomicMin(&miny[bj * 128 + tid], __float_as_uint(fmaxf(c, 0.f)));
  } else {
    const int r = tid - 128;
    float vmin = fminf(rowminLDS[0][r], rowminLDS[1][r]);
    atomicMin(&minx[bi * 128 + r], __float_as_uint(fmaxf(vmin, 0.f)));
  }
}

// ------------------------------------------------------------- finalize ----
__global__ __launch_bounds__(256) void finalize_kernel(
    const unsigned int* __restrict__ minx, const unsigned int* __restrict__ miny,
    float* __restrict__ out)
{
  // all stored patterns are non-negative floats; reinterpret directly
  const f32x4* mx = (const f32x4*)minx;
  const f32x4* my = (const f32x4*)miny;
  float s = 0.f;
  for (int i = threadIdx.x; i < NPTS / 4; i += 256) {
    f32x4 a = mx[i], b = my[i];
    s += (a[0] + a[1] + a[2] + a[3]) + (b[0] + b[1] + b[2] + b[3]);
  }
  #pragma unroll
  for (int m = 32; m >= 1; m >>= 1) s += __shfl_xor(s, m);
  __shared__ float partial[4];
  if ((threadIdx.x & 63) == 0) partial[threadIdx.x >> 6] = s;
  __syncthreads();
  if (threadIdx.x == 0)
    out[0] = (partial[0] + partial[1] + partial[2] + partial[3]) * (1.0f / (float)NPTS);
}

// ---------------------------------------------------------------- launch ----
extern "C" void kernel_launch(void* const* d_in, const int* in_sizes, int n_in,
                              void* d_out, int out_size, void* d_ws, size_t ws_size,
                              hipStream_t stream) {
  (void)in_sizes; (void)n_in; (void)out_size; (void)ws_size;
  const float* x = (const float*)d_in[0];
  const float* y = (const float*)d_in[1];
  char* ws = (char*)d_ws;

  // ws layout: Xc 2MB | Yc 2MB | x2 32KB | y2 32KB | minx 32KB | miny 32KB
  unsigned short* Xc  = (unsigned short*)(ws);
  unsigned short* Yc  = (unsigned short*)(ws + 2097152);
  float*          x2  = (float*)(ws + 4194304);
  float*          y2  = (float*)(ws + 4227072);
  unsigned int*   mnx = (unsigned int*)(ws + 4259840);
  unsigned int*   mny = (unsigned int*)(ws + 4292608);
  float*          out = (float*)d_out;

  prep_kernel<<<2048, 256, 0, stream>>>(x, y, Xc, Yc, x2, y2, mnx, mny);
  chamfer_gemm<<<4096, 256, 0, stream>>>(Xc, Yc, x2, y2, mnx, mny);
  finalize_kernel<<<1, 256, 0, stream>>>(mnx, mny, out);
}